// Round 15
// baseline (483.637 us; speedup 1.0000x reference)
//
#include <hip/hip_runtime.h>
#include <hip/hip_bf16.h>
#include <math.h>

#define NN 20000
#define EE 320000
#define IND 128
#define HH 6
#define CC 64
#define HCC 384
#define NCC 16
#define NGG 64

typedef __bf16 bf16x8 __attribute__((ext_vector_type(8)));
typedef float f32x4 __attribute__((ext_vector_type(4)));
typedef float f32x2 __attribute__((ext_vector_type(2)));
typedef unsigned short ushort_t;
typedef unsigned int uint_t;

#define LOG2E 1.44269504088896f

__device__ inline ushort_t f2bf(float f) {
    union { float f; uint_t u; } x; x.f = f;
    uint_t r = (x.u + 0x7FFF + ((x.u >> 16) & 1)) >> 16;
    return (ushort_t)r;
}
// 8 packed bf16 (uint4) -> 4 f32x2 (pairs) for packed-f32 VALU
__device__ inline void bf8cvt2(uint4 v, f32x2* f) {
    union { uint_t u; float x; } a, b;
    a.u = v.x << 16; b.u = v.x & 0xFFFF0000u; f[0] = (f32x2){a.x, b.x};
    a.u = v.y << 16; b.u = v.y & 0xFFFF0000u; f[1] = (f32x2){a.x, b.x};
    a.u = v.z << 16; b.u = v.z & 0xFFFF0000u; f[2] = (f32x2){a.x, b.x};
    a.u = v.w << 16; b.u = v.w & 0xFFFF0000u; f[3] = (f32x2){a.x, b.x};
}

// DPP cross-lane add (VALU, no DS pipe). CTRL: 0xB1=xor1, 0x4E=xor2,
// 0x141=row_half_mirror (==xor4 once quad-uniform), 0x140=row_mirror (==xor8).
template <int CTRL>
__device__ inline float dppadd(float x) {
    int y = __builtin_amdgcn_mov_dpp(__builtin_bit_cast(int, x), CTRL, 0xF, 0xF, true);
    return x + __builtin_bit_cast(float, y);
}

// async global->LDS: lane L writes lds+16*L
__device__ inline void load_lds16(const ushort_t* g, ushort_t* l) {
    __builtin_amdgcn_global_load_lds(
        (const __attribute__((address_space(1))) void*)g,
        (__attribute__((address_space(3))) void*)l, 16, 0, 0);
}

// ---------------- utility kernels ----------------

__global__ void zero_init_kernel(int* counts, float* pooled, int n, int np) {
    int t = blockIdx.x * blockDim.x + threadIdx.x;
    if (t < n) counts[t] = 0;
    if (t < np) pooled[t] = 0.0f;
}

__global__ void count_kernel(const int* __restrict__ ei, int* __restrict__ counts, int E) {
    int t = blockIdx.x * blockDim.x + threadIdx.x;
    if (t < E) atomicAdd(&counts[ei[E + t]], 1);
}

// exclusive scan of (counts[i]+1) -> offsets/cursor, plus a descending-degree
// counting-sort permutation (equal-degree nodes grouped => balanced gat6 waves).
__global__ void scan_kernel(const int* __restrict__ counts, int* __restrict__ offsets,
                            int* __restrict__ cursor, int* __restrict__ perm, int n) {
    __shared__ int part[1024];
    __shared__ int buck[256];
    __shared__ int bcur[256];
    int t = threadIdx.x;
    if (t < 256) buck[t] = 0;
    __syncthreads();
    int per = (n + 1023) / 1024;
    int base = t * per;
    int sum = 0;
    for (int j = 0; j < per; ++j) {
        int idx = base + j;
        if (idx < n) {
            int deg = counts[idx] + 1;
            sum += deg;
            atomicAdd(&buck[min(deg, 255)], 1);
        }
    }
    part[t] = sum;
    __syncthreads();
    for (int off = 1; off < 1024; off <<= 1) {
        int v = (t >= off) ? part[t - off] : 0;
        __syncthreads();
        part[t] += v;
        __syncthreads();
    }
    if (t == 0) {
        int run = 0;
        for (int b = 255; b >= 0; --b) { bcur[b] = run; run += buck[b]; }
    }
    __syncthreads();
    int run = (t == 0) ? 0 : part[t - 1];
    for (int j = 0; j < per; ++j) {
        int idx = base + j;
        if (idx < n) {
            int deg = counts[idx] + 1;
            offsets[idx] = run;
            cursor[idx] = run;
            run += deg;
            int pos = atomicAdd(&bcur[min(deg, 255)], 1);
            perm[pos] = idx;
        }
    }
    if (t == 1023) offsets[n] = part[1023];
}

__global__ void fill_kernel(const int* __restrict__ ei, int* __restrict__ cursor,
                            int* __restrict__ srcs, int E, int n) {
    int t = blockIdx.x * blockDim.x + threadIdx.x;
    if (t < E) {
        int s = ei[t];
        int d = ei[E + t];
        int slot = atomicAdd(&cursor[d], 1);
        srcs[slot] = s;
    } else if (t < E + n) {
        int i = t - E;
        int slot = atomicAdd(&cursor[i], 1);
        srcs[slot] = i;
    }
}

// ---------------- weight/input prep: fp32 -> bf16 TRANSPOSED ([N][K]) ----------------
#define WBIG (1152 * IND)
#define WC1 (768 * HCC)
#define WC2 (192 * HCC)
#define XB_N (NN * IND)
#define PREP_TOTAL (WBIG + WC1 + WC2 + XB_N + 1152 + 768 + 192)

__global__ void prep_kernel(const float* __restrict__ x, const float* __restrict__ inp_w,
    const float* __restrict__ l0wl, const float* __restrict__ l0wr,
    const float* __restrict__ l1wl, const float* __restrict__ l1wr,
    const float* __restrict__ l2wl, const float* __restrict__ l2wr,
    const float* __restrict__ resw,
    const float* __restrict__ inp_b,
    const float* __restrict__ l0bl, const float* __restrict__ l0br,
    const float* __restrict__ l1bl, const float* __restrict__ l1br,
    const float* __restrict__ l2bl, const float* __restrict__ l2br,
    ushort_t* wBig, ushort_t* wC1, ushort_t* wC2, ushort_t* xb,
    float* bBig, float* bC1, float* bC2)
{
    int i = blockIdx.x * blockDim.x + threadIdx.x;
    if (i >= PREP_TOTAL) return;
    if (i < WBIG) {
        int col = i >> 7, k = i & 127;
        float v;
        if (col < 384)      v = inp_w[k * 384 + col];
        else if (col < 768) v = l0wl[k * 384 + (col - 384)];
        else                v = l0wr[k * 384 + (col - 768)];
        wBig[i] = f2bf(v); return;
    }
    i -= WBIG;
    if (i < WC1) {
        int col = i / 384, k = i - col * 384;
        float v = col < 384 ? l1wl[k * 384 + col] : l1wr[k * 384 + (col - 384)];
        wC1[i] = f2bf(v); return;
    }
    i -= WC1;
    if (i < WC2) {
        int col = i / 384, k = i - col * 384;
        float v;
        if (col < 64)       v = resw[k * 64 + col];
        else if (col < 128) v = l2wl[k * 64 + (col - 64)];
        else                v = l2wr[k * 64 + (col - 128)];
        wC2[i] = f2bf(v); return;
    }
    i -= WC2;
    if (i < XB_N) { xb[i] = f2bf(x[i]); return; }
    i -= XB_N;
    if (i < 1152) {
        float v;
        if (i < 384)      v = inp_b[i];
        else if (i < 768) v = l0bl[i - 384];
        else              v = l0br[i - 768];
        bBig[i] = v; return;
    }
    i -= 1152;
    if (i < 768) { bC1[i] = i < 384 ? l1bl[i] : l1br[i - 384]; return; }
    i -= 768;
    if (i < 192) {
        float v;
        if (i < 64)       v = 0.0f;
        else if (i < 128) v = l2bl[i - 64];
        else              v = l2br[i - 128];
        bC2[i] = v; return;
    }
}

// ---------------- bf16 MFMA GEMM: A direct-to-register, B-only LDS, BK=64 ----------------
__global__ __launch_bounds__(256) void gemm_mfma(
    const ushort_t* __restrict__ A, const ushort_t* __restrict__ BT,
    const float* __restrict__ bias,
    float* __restrict__ Cf, ushort_t* __restrict__ Cb1, int ld1,
    ushort_t* __restrict__ Cb2, int ld2, int split,
    int M, int N, int K)
{
    __shared__ ushort_t Bs[2][2][128 * 32];   // [buf][k-half][row*32+k]
    int t = threadIdx.x;
    int w = t >> 6, L = t & 63;
    int m0 = blockIdx.x * 128, n0 = blockIdx.y * 128;
    int q = L >> 4, r16 = L & 15;

    f32x4 acc[2][8];
#pragma unroll
    for (int a = 0; a < 2; ++a)
#pragma unroll
        for (int b = 0; b < 8; ++b) acc[a][b] = (f32x4){0.f, 0.f, 0.f, 0.f};

    int lr = L >> 2;
    int lc = (L & 3) * 8;
    int rB0 = min(n0 + w * 32 + lr, N - 1);
    int rB1 = min(n0 + w * 32 + 16 + lr, N - 1);
    const ushort_t* gB0 = BT + (size_t)rB0 * K + lc;
    const ushort_t* gB1 = BT + (size_t)rB1 * K + lc;
    int oB0 = (w * 32) * 32;
    int oB1 = (w * 32 + 16) * 32;

    int rA0 = min(m0 + w * 32 + r16, M - 1);
    int rA1 = min(m0 + w * 32 + 16 + r16, M - 1);
    const ushort_t* pA0 = A + (size_t)rA0 * K + q * 8;
    const ushort_t* pA1 = A + (size_t)rA1 * K + q * 8;

    load_lds16(gB0, &Bs[0][0][oB0]);
    load_lds16(gB1, &Bs[0][0][oB1]);
    load_lds16(gB0 + 32, &Bs[0][1][oB0]);
    load_lds16(gB1 + 32, &Bs[0][1][oB1]);
    gB0 += 64; gB1 += 64;
    bf16x8 a0 = *(const bf16x8*)pA0;
    bf16x8 a2 = *(const bf16x8*)(pA0 + 32);
    bf16x8 a1 = *(const bf16x8*)pA1;
    bf16x8 a3 = *(const bf16x8*)(pA1 + 32);
    pA0 += 64; pA1 += 64;

    int buf = 0;
    for (int k0 = 0; k0 < K; k0 += 64) {
        __syncthreads();
        bool more = (k0 + 64 < K);
        if (more) {
            int nb = buf ^ 1;
            load_lds16(gB0, &Bs[nb][0][oB0]);
            load_lds16(gB1, &Bs[nb][0][oB1]);
            load_lds16(gB0 + 32, &Bs[nb][1][oB0]);
            load_lds16(gB1 + 32, &Bs[nb][1][oB1]);
            gB0 += 64; gB1 += 64;
        }
        bf16x8 na0, na1, na2, na3;
        if (more) {
            na0 = *(const bf16x8*)pA0;
            na2 = *(const bf16x8*)(pA0 + 32);
            na1 = *(const bf16x8*)pA1;
            na3 = *(const bf16x8*)(pA1 + 32);
            pA0 += 64; pA1 += 64;
        }
#pragma unroll
        for (int ct = 0; ct < 8; ++ct) {
            bf16x8 blo = *(const bf16x8*)&Bs[buf][0][(ct * 16 + r16) * 32 + q * 8];
            bf16x8 bhi = *(const bf16x8*)&Bs[buf][1][(ct * 16 + r16) * 32 + q * 8];
            acc[0][ct] = __builtin_amdgcn_mfma_f32_16x16x32_bf16(a0, blo, acc[0][ct], 0, 0, 0);
            acc[1][ct] = __builtin_amdgcn_mfma_f32_16x16x32_bf16(a1, blo, acc[1][ct], 0, 0, 0);
            acc[0][ct] = __builtin_amdgcn_mfma_f32_16x16x32_bf16(a2, bhi, acc[0][ct], 0, 0, 0);
            acc[1][ct] = __builtin_amdgcn_mfma_f32_16x16x32_bf16(a3, bhi, acc[1][ct], 0, 0, 0);
        }
        if (more) { a0 = na0; a1 = na1; a2 = na2; a3 = na3; }
        buf ^= 1;
    }
#pragma unroll
    for (int rt = 0; rt < 2; ++rt) {
#pragma unroll
        for (int ct = 0; ct < 8; ++ct) {
            int col = n0 + ct * 16 + r16;
            if (col < N) {
                float bv = bias ? bias[col] : 0.0f;
#pragma unroll
                for (int rr = 0; rr < 4; ++rr) {
                    int row = m0 + w * 32 + rt * 16 + q * 4 + rr;
                    if (row < M) {
                        float v = acc[rt][ct][rr] + bv;
                        if (col < split) {
                            if (Cf) Cf[(size_t)row * ld1 + col] = v;
                            else    Cb1[(size_t)row * ld1 + col] = f2bf(v);
                        } else {
                            Cb2[(size_t)row * ld2 + (col - split)] = f2bf(v);
                        }
                    }
                }
            }
        }
    }
}

// ---------------- GATv2 H=6: single-pass, exp2-folded softmax, DPP reduce, pipelined ----------------
// att pre-scaled by log2(e): exp(e) == exp2(e_scaled). Node order via degree-sorted perm.
__global__ __launch_bounds__(256) void gat6_kernel(
    const ushort_t* __restrict__ cat, const float* __restrict__ att,
    const float* __restrict__ bias, const ushort_t* __restrict__ resB,
    ushort_t* __restrict__ outB,
    const int* __restrict__ offsets, const int* __restrict__ srcs,
    const int* __restrict__ perm, int n)
{
    int wid = (blockIdx.x * blockDim.x + threadIdx.x) >> 6;
    if (wid >= n) return;
    int lane = threadIdx.x & 63;
    int h = lane >> 3, c8 = lane & 7;
    int off = h * 64 + c8 * 8;
    bool hv = h < HH;
    int i = perm[wid];
    int beg = offsets[i], end = offsets[i + 1];

    f32x2 xr2[4], att2[4];
    {
        uint4 v = make_uint4(0u, 0u, 0u, 0u);
        if (hv) v = *(const uint4*)(cat + (size_t)i * 768 + 384 + off);
        bf8cvt2(v, xr2);
    }
#pragma unroll
    for (int j = 0; j < 4; ++j) {
        float a0 = hv ? att[off + 2 * j] * LOG2E : 0.0f;
        float a1 = hv ? att[off + 2 * j + 1] * LOG2E : 0.0f;
        att2[j] = (f32x2){a0, a1};
    }

    float s = 0.0f;
    f32x2 acc2[4];
#pragma unroll
    for (int j = 0; j < 4; ++j) acc2[j] = (f32x2){0.f, 0.f};

    const uint4 z = make_uint4(0u, 0u, 0u, 0u);
    int deg = end - beg;
    int npair = deg >> 1;
    bool odd = (deg & 1) != 0;

    uint4 cA = z, cB = z;
    int iA1 = 0, iB1 = 0;

    if (npair > 0) {
        int iA0 = srcs[beg], iB0 = srcs[beg + 1];
        if (npair > 1)      { iA1 = srcs[beg + 2]; iB1 = srcs[beg + 3]; }
        else if (odd)       { iA1 = srcs[beg + 2]; }
        if (hv) {
            cA = *(const uint4*)(cat + (size_t)iA0 * 768 + off);
            cB = *(const uint4*)(cat + (size_t)iB0 * 768 + off);
        }
    } else if (odd) {
        int i0 = srcs[beg];
        if (hv) cA = *(const uint4*)(cat + (size_t)i0 * 768 + off);
    }

    for (int g = 0; g < npair; ++g) {
        int base2 = beg + 2 * (g + 2);
        int niA = 0, niB = 0;
        if (g + 2 < npair)                { niA = srcs[base2]; niB = srcs[base2 + 1]; }
        else if (g + 2 == npair && odd)   { niA = srcs[base2]; }
        uint4 nA = z, nB = z;
        bool haveN = (g + 1 < npair);
        bool haveT = (g + 1 == npair) && odd;
        if (hv) {
            if (haveN) {
                nA = *(const uint4*)(cat + (size_t)iA1 * 768 + off);
                nB = *(const uint4*)(cat + (size_t)iB1 * 768 + off);
            } else if (haveT) {
                nA = *(const uint4*)(cat + (size_t)iA1 * 768 + off);
            }
        }
        f32x2 xlA[4], xlB[4];
        bf8cvt2(cA, xlA);
        bf8cvt2(cB, xlB);
        f32x2 pA2 = (f32x2){0.f, 0.f}, pB2 = (f32x2){0.f, 0.f};
#pragma unroll
        for (int j = 0; j < 4; ++j) {
            f32x2 ta = xlA[j] + xr2[j];
            ta = __builtin_elementwise_max(ta, ta * 0.2f);
            pA2 += ta * att2[j];
            f32x2 tb = xlB[j] + xr2[j];
            tb = __builtin_elementwise_max(tb, tb * 0.2f);
            pB2 += tb * att2[j];
        }
        float pA = pA2.x + pA2.y, pB = pB2.x + pB2.y;
        pA = dppadd<0xB1>(pA);
        pB = dppadd<0xB1>(pB);
        pA = dppadd<0x4E>(pA);
        pB = dppadd<0x4E>(pB);
        pA = dppadd<0x141>(pA);
        pB = dppadd<0x141>(pB);
        float wA = __builtin_amdgcn_exp2f(pA);
        float wB = __builtin_amdgcn_exp2f(pB);
        s += wA + wB;
        f32x2 wA2 = (f32x2){wA, wA}, wB2 = (f32x2){wB, wB};
#pragma unroll
        for (int j = 0; j < 4; ++j) {
            acc2[j] += wA2 * xlA[j];
            acc2[j] += wB2 * xlB[j];
        }
        cA = nA; cB = nB;
        iA1 = niA; iB1 = niB;
    }
    if (odd) {
        f32x2 xl[4];
        bf8cvt2(cA, xl);
        f32x2 pp2 = (f32x2){0.f, 0.f};
#pragma unroll
        for (int j = 0; j < 4; ++j) {
            f32x2 tv = xl[j] + xr2[j];
            tv = __builtin_elementwise_max(tv, tv * 0.2f);
            pp2 += tv * att2[j];
        }
        float pp = pp2.x + pp2.y;
        pp = dppadd<0xB1>(pp);
        pp = dppadd<0x4E>(pp);
        pp = dppadd<0x141>(pp);
        float wE = __builtin_amdgcn_exp2f(pp);
        s += wE;
        f32x2 w2 = (f32x2){wE, wE};
#pragma unroll
        for (int j = 0; j < 4; ++j) acc2[j] += w2 * xl[j];
    }

    if (hv) {
        float inv = 1.0f / (s + 1e-16f);
        size_t ob = (size_t)i * HCC + off;
        uint4 rv = *(const uint4*)(resB + ob);
        f32x2 rr[4];
        bf8cvt2(rv, rr);
        ushort_t u[8];
#pragma unroll
        for (int j = 0; j < 4; ++j) {
            float v0 = acc2[j].x * inv + bias[off + 2 * j];
            float v1 = acc2[j].y * inv + bias[off + 2 * j + 1];
            v0 = v0 > 0.0f ? v0 : expm1f(v0);
            v1 = v1 > 0.0f ? v1 : expm1f(v1);
            u[2 * j]     = f2bf(v0 + rr[j].x);
            u[2 * j + 1] = f2bf(v1 + rr[j].y);
        }
        *(uint4*)(outB + ob) = *(uint4*)u;
    }
}

// ---------------- GATv2 H=1: single-pass exp2-folded, DPP reduce, prefetched ----------------
// Linear wid (no perm): short loop, write coalescing matters more than balance.
__global__ __launch_bounds__(256) void gat1_kernel(
    const ushort_t* __restrict__ cat, const float* __restrict__ att,
    const float* __restrict__ bias, const float* __restrict__ res,
    float* __restrict__ out,
    const int* __restrict__ offsets, const int* __restrict__ srcs, int n)
{
    int wid = (blockIdx.x * blockDim.x + threadIdx.x) >> 6;
    if (wid >= n) return;
    int lane = threadIdx.x & 63;
    int e8 = lane >> 3, c8 = lane & 7;
    int i = wid;
    int beg = offsets[i], end = offsets[i + 1];

    f32x2 xr2[4], att2[4];
    {
        uint4 v = *(const uint4*)(cat + (size_t)i * 128 + 64 + c8 * 8);
        bf8cvt2(v, xr2);
    }
#pragma unroll
    for (int j = 0; j < 4; ++j)
        att2[j] = (f32x2){att[c8 * 8 + 2 * j] * LOG2E, att[c8 * 8 + 2 * j + 1] * LOG2E};

    float s = 0.0f;
    f32x2 acc2[4];
#pragma unroll
    for (int j = 0; j < 4; ++j) acc2[j] = (f32x2){0.f, 0.f};

    const uint4 z = make_uint4(0u, 0u, 0u, 0u);
    int p = beg + e8;
    bool val = p < end;
    int sj = val ? srcs[p] : i;
    uint4 v = *(const uint4*)(cat + (size_t)sj * 128 + c8 * 8);

    for (int p0 = beg; p0 < end; p0 += 8) {
        uint4 nv = z;
        bool nval = false;
        if (p0 + 8 < end) {
            int np = p0 + 8 + e8;
            nval = np < end;
            int nsj = nval ? srcs[np] : i;
            nv = *(const uint4*)(cat + (size_t)nsj * 128 + c8 * 8);
        }
        f32x2 xl[4];
        bf8cvt2(v, xl);
        f32x2 pp2 = (f32x2){0.f, 0.f};
#pragma unroll
        for (int j = 0; j < 4; ++j) {
            f32x2 tv = xl[j] + xr2[j];
            tv = __builtin_elementwise_max(tv, tv * 0.2f);
            pp2 += tv * att2[j];
        }
        float partial = pp2.x + pp2.y;
        partial = dppadd<0xB1>(partial);
        partial = dppadd<0x4E>(partial);
        partial = dppadd<0x141>(partial);
        float wE = val ? __builtin_amdgcn_exp2f(partial) : 0.0f;
        s += wE;
        f32x2 w2 = (f32x2){wE, wE};
#pragma unroll
        for (int j = 0; j < 4; ++j) acc2[j] += w2 * xl[j];
        v = nv;
        val = nval;
    }

    s = dppadd<0x140>(s);
    s += __shfl_xor(s, 16, 64);
    s += __shfl_xor(s, 32, 64);
#pragma unroll
    for (int j = 0; j < 4; ++j) {
        acc2[j].x += __shfl_xor(acc2[j].x, 8, 64);
        acc2[j].y += __shfl_xor(acc2[j].y, 8, 64);
        acc2[j].x += __shfl_xor(acc2[j].x, 16, 64);
        acc2[j].y += __shfl_xor(acc2[j].y, 16, 64);
        acc2[j].x += __shfl_xor(acc2[j].x, 32, 64);
        acc2[j].y += __shfl_xor(acc2[j].y, 32, 64);
    }
    if (e8 == 0) {
        float inv = 1.0f / (s + 1e-16f);
        size_t ob = (size_t)i * CC + c8 * 8;
        float4 r0 = *(const float4*)(res + ob);
        float4 r1 = *(const float4*)(res + ob + 4);
        float rr[8] = {r0.x, r0.y, r0.z, r0.w, r1.x, r1.y, r1.z, r1.w};
        float av[8] = {acc2[0].x, acc2[0].y, acc2[1].x, acc2[1].y,
                       acc2[2].x, acc2[2].y, acc2[3].x, acc2[3].y};
#pragma unroll
        for (int j = 0; j < 8; ++j) {
            float v2 = av[j] * inv + bias[c8 * 8 + j];
            v2 = v2 > 0.0f ? v2 : expm1f(v2);
            av[j] = v2 + rr[j];
        }
        *(float4*)(out + ob) = make_float4(av[0], av[1], av[2], av[3]);
        *(float4*)(out + ob + 4) = make_float4(av[4], av[5], av[6], av[7]);
    }
}

// ---------------- pooling (batch is sorted) ----------------
__global__ void pool_kernel(const float* __restrict__ h, const int* __restrict__ batch,
                            float* __restrict__ pooled, int n) {
    const int CHUNK = 128;
    int start = blockIdx.x * CHUNK;
    int lane = threadIdx.x;  // 64
    if (start >= n) return;
    int end = start + CHUNK;
    if (end > n) end = n;
    float acc = 0.0f;
    int cur = batch[start];
    for (int i = start; i < end; ++i) {
        int g = batch[i];
        if (g != cur) {
            atomicAdd(&pooled[cur * 64 + lane], acc);
            acc = 0.0f;
            cur = g;
        }
        acc += h[(size_t)i * 64 + lane];
    }
    atomicAdd(&pooled[cur * 64 + lane], acc);
}

// ---------------- dense head ----------------
__global__ void head_kernel(const float* __restrict__ pooled,
                            const float* __restrict__ d1w, const float* __restrict__ d1b,
                            const float* __restrict__ bng, const float* __restrict__ bnb,
                            const float* __restrict__ bnm, const float* __restrict__ bnv,
                            const float* __restrict__ d2w, const float* __restrict__ d2b,
                            float* __restrict__ zout) {
    __shared__ float z1[64 * 64];
    int t = threadIdx.x;  // 256
    for (int idx = t; idx < 64 * 64; idx += 256) {
        int r = idx >> 6, c = idx & 63;
        float acc = d1b[c];
        for (int k = 0; k < 64; ++k) acc += pooled[r * 64 + k] * d1w[k * 64 + c];
        acc = (acc - bnm[c]) / sqrtf(bnv[c] + 1e-5f) * bng[c] + bnb[c];
        z1[idx] = acc > 0.0f ? acc : 0.0f;
    }
    __syncthreads();
    for (int idx = t; idx < 64 * NCC; idx += 256) {
        int r = idx >> 4, c = idx & 15;
        float acc = d2b[c];
        for (int k = 0; k < 64; ++k) acc += z1[r * 64 + k] * d2w[k * NCC + c];
        zout[idx] = acc;
    }
}

// ---------------- launcher ----------------

extern "C" void kernel_launch(void* const* d_in, const int* in_sizes, int n_in,
                              void* d_out, int out_size, void* d_ws, size_t ws_size,
                              hipStream_t stream) {
    const int N = NN, E = EE, C = CC, HC = HCC, NG = NGG;
    const int EN = E + N;

    const float* x     = (const float*)d_in[0];
    const int*   ei    = (const int*)d_in[1];
    const int*   batch = (const int*)d_in[2];
    const float* inp_w = (const float*)d_in[3];
    const float* inp_b = (const float*)d_in[4];
    const float* l0_wl = (const float*)d_in[5];
    const float* l0_bl = (const float*)d_in[6];
    const float* l0_wr = (const float*)d_in[7];
    const float* l0_br = (const float*)d_in[8];
    const float* l0_att = (const float*)d_in[9];
    const float* l0_bias = (const float*)d_in[10];
    const float* l1_wl = (const float*)d_in[11];
    const float* l1_bl = (const float*)d_in[12];
    const float* l1_wr = (const float*)d_in[13];
    const float* l1_br = (const float*)d_in[14];
    const float* l1_att = (const float*)d_in[15];
    const float* l1_bias = (const float*)d_in[16];
    const float* l2_wl = (const float*)d_in[17];
    const float* l2_bl = (const float*)d_in[18];
    const float* l2_wr = (const float*)d_in[19];
    const float* l2_br = (const float*)d_in[20];
    const float* l2_att = (const float*)d_in[21];
    const float* l2_bias = (const float*)d_in[22];
    const float* res_w = (const float*)d_in[23];
    const float* d1_w = (const float*)d_in[24];
    const float* d1_b = (const float*)d_in[25];
    const float* bn_g = (const float*)d_in[26];
    const float* bn_b = (const float*)d_in[27];
    const float* bn_m = (const float*)d_in[28];
    const float* bn_v = (const float*)d_in[29];
    const float* d2_w = (const float*)d_in[30];
    const float* d2_b = (const float*)d_in[31];

    float* out = (float*)d_out;

    char* ws = (char*)d_ws;
    size_t off = 0;
    auto alloc = [&](size_t bytes) -> void* {
        void* p = ws + off;
        off += (bytes + 255) & ~(size_t)255;
        return p;
    };
    ushort_t* bufH_b  = (ushort_t*)alloc((size_t)N * HC * 2);
    ushort_t* cat01_b = (ushort_t*)alloc((size_t)N * 768 * 2 + 2048);
    ushort_t* xres_b  = (ushort_t*)alloc((size_t)N * HC * 2);
    ushort_t* cat2_b  = (ushort_t*)alloc((size_t)N * 128 * 2);
    float*    bufRes  = (float*)alloc((size_t)N * C * 4);
    ushort_t* xb      = (ushort_t*)alloc((size_t)N * IND * 2);
    ushort_t* wBig    = (ushort_t*)alloc((size_t)WBIG * 2);
    ushort_t* wC1     = (ushort_t*)alloc((size_t)WC1 * 2);
    ushort_t* wC2     = (ushort_t*)alloc((size_t)WC2 * 2);
    float*    bBig    = (float*)alloc((size_t)1152 * 4);
    float*    bC1     = (float*)alloc((size_t)768 * 4);
    float*    bC2     = (float*)alloc((size_t)192 * 4);
    int*      counts  = (int*)alloc((size_t)N * 4);
    int*      cursor  = (int*)alloc((size_t)N * 4);
    int*      offsets = (int*)alloc((size_t)(N + 1) * 4);
    int*      perm    = (int*)alloc((size_t)N * 4);
    int*      srcs    = (int*)alloc((size_t)EN * 4);
    float*    pooled  = (float*)alloc((size_t)NG * C * 4);

    int zi_n = N > NG * C ? N : NG * C;
    zero_init_kernel<<<(zi_n + 255) / 256, 256, 0, stream>>>(counts, pooled, N, NG * C);
    count_kernel<<<(E + 255) / 256, 256, 0, stream>>>(ei, counts, E);
    scan_kernel<<<1, 1024, 0, stream>>>(counts, offsets, cursor, perm, N);
    fill_kernel<<<(EN + 255) / 256, 256, 0, stream>>>(ei, cursor, srcs, E, N);
    prep_kernel<<<(PREP_TOTAL + 255) / 256, 256, 0, stream>>>(
        x, inp_w, l0_wl, l0_wr, l1_wl, l1_wr, l2_wl, l2_wr, res_w,
        inp_b, l0_bl, l0_br, l1_bl, l1_br, l2_bl, l2_br,
        wBig, wC1, wC2, xb, bBig, bC1, bC2);

    dim3 blk(256);
    int mtiles = (N + 127) / 128;
    int gatBlocks = (N * 64 + 255) / 256;

    // fused: [x_res | l0_xl | l0_xr] = xb @ wBig (all bf16 out; split at 384)
    gemm_mfma<<<dim3(mtiles, 9), blk, 0, stream>>>(xb, wBig, bBig,
        nullptr, xres_b, HC, cat01_b, 768, 384, N, 1152, IND);
    gat6_kernel<<<gatBlocks, blk, 0, stream>>>(cat01_b, l0_att, l0_bias,
                                               xres_b, bufH_b, offsets, srcs, perm, N);
    // layer 1: [l1_xl | l1_xr] = h0 @ wC1
    gemm_mfma<<<dim3(mtiles, 6), blk, 0, stream>>>(bufH_b, wC1, bC1,
        nullptr, nullptr, 0, cat01_b, 768, 0, N, 768, HC);
    gat6_kernel<<<gatBlocks, blk, 0, stream>>>(cat01_b, l1_att, l1_bias,
                                               bufH_b, bufH_b, offsets, srcs, perm, N);
    // fused: [res | l2_xl | l2_xr] = h1 @ wC2 (res fp32, rest bf16)
    gemm_mfma<<<dim3(mtiles, 2), blk, 0, stream>>>(bufH_b, wC2, bC2,
        bufRes, nullptr, C, cat2_b, 128, 64, N, 192, HC);
    gat1_kernel<<<gatBlocks, blk, 0, stream>>>(cat2_b, l2_att, l2_bias,
                                               bufRes, out, offsets, srcs, N);
    // pooling + head
    pool_kernel<<<(N + 127) / 128, 64, 0, stream>>>(out, batch, pooled, N);
    head_kernel<<<1, 256, 0, stream>>>(pooled, d1_w, d1_b, bn_g, bn_b, bn_m, bn_v,
                                       d2_w, d2_b, out + (size_t)N * C);
}

// Round 16
// 471.633 us; speedup vs baseline: 1.0255x; 1.0255x over previous
//
#include <hip/hip_runtime.h>
#include <hip/hip_bf16.h>
#include <math.h>

#define NN 20000
#define EE 320000
#define IND 128
#define HH 6
#define CC 64
#define HCC 384
#define NCC 16
#define NGG 64

typedef __bf16 bf16x8 __attribute__((ext_vector_type(8)));
typedef float f32x4 __attribute__((ext_vector_type(4)));
typedef float f32x2 __attribute__((ext_vector_type(2)));
typedef unsigned short ushort_t;
typedef unsigned int uint_t;

#define LOG2E 1.44269504088896f

__device__ inline ushort_t f2bf(float f) {
    union { float f; uint_t u; } x; x.f = f;
    uint_t r = (x.u + 0x7FFF + ((x.u >> 16) & 1)) >> 16;
    return (ushort_t)r;
}
// 8 packed bf16 (uint4) -> 4 f32x2 (pairs) for packed-f32 VALU
__device__ inline void bf8cvt2(uint4 v, f32x2* f) {
    union { uint_t u; float x; } a, b;
    a.u = v.x << 16; b.u = v.x & 0xFFFF0000u; f[0] = (f32x2){a.x, b.x};
    a.u = v.y << 16; b.u = v.y & 0xFFFF0000u; f[1] = (f32x2){a.x, b.x};
    a.u = v.z << 16; b.u = v.z & 0xFFFF0000u; f[2] = (f32x2){a.x, b.x};
    a.u = v.w << 16; b.u = v.w & 0xFFFF0000u; f[3] = (f32x2){a.x, b.x};
}

// DPP cross-lane add (VALU, no DS pipe). CTRL: 0xB1=xor1, 0x4E=xor2,
// 0x141=row_half_mirror (==xor4 once quad-uniform), 0x140=row_mirror (==xor8).
template <int CTRL>
__device__ inline float dppadd(float x) {
    int y = __builtin_amdgcn_mov_dpp(__builtin_bit_cast(int, x), CTRL, 0xF, 0xF, true);
    return x + __builtin_bit_cast(float, y);
}

// async global->LDS: lane L writes lds+16*L
__device__ inline void load_lds16(const ushort_t* g, ushort_t* l) {
    __builtin_amdgcn_global_load_lds(
        (const __attribute__((address_space(1))) void*)g,
        (__attribute__((address_space(3))) void*)l, 16, 0, 0);
}

// ---------------- utility kernels ----------------

__global__ void zero_init_kernel(int* counts, float* pooled, int n, int np) {
    int t = blockIdx.x * blockDim.x + threadIdx.x;
    if (t < n) counts[t] = 0;
    if (t < np) pooled[t] = 0.0f;
}

__global__ void count_kernel(const int* __restrict__ ei, int* __restrict__ counts, int E) {
    int t = blockIdx.x * blockDim.x + threadIdx.x;
    if (t < E) atomicAdd(&counts[ei[E + t]], 1);
}

// exclusive scan of (counts[i]+1) -> offsets/cursor (r13 light version, no sort)
__global__ void scan_kernel(const int* __restrict__ counts, int* __restrict__ offsets,
                            int* __restrict__ cursor, int n) {
    __shared__ int part[1024];
    int t = threadIdx.x;
    int per = (n + 1023) / 1024;
    int base = t * per;
    int sum = 0;
    for (int j = 0; j < per; ++j) {
        int idx = base + j;
        if (idx < n) sum += counts[idx] + 1;
    }
    part[t] = sum;
    __syncthreads();
    for (int off = 1; off < 1024; off <<= 1) {
        int v = (t >= off) ? part[t - off] : 0;
        __syncthreads();
        part[t] += v;
        __syncthreads();
    }
    int run = (t == 0) ? 0 : part[t - 1];
    for (int j = 0; j < per; ++j) {
        int idx = base + j;
        if (idx < n) {
            int deg = counts[idx] + 1;
            offsets[idx] = run;
            cursor[idx] = run;
            run += deg;
        }
    }
    if (t == 1023) offsets[n] = part[1023];
}

__global__ void fill_kernel(const int* __restrict__ ei, int* __restrict__ cursor,
                            int* __restrict__ srcs, int E, int n) {
    int t = blockIdx.x * blockDim.x + threadIdx.x;
    if (t < E) {
        int s = ei[t];
        int d = ei[E + t];
        int slot = atomicAdd(&cursor[d], 1);
        srcs[slot] = s;
    } else if (t < E + n) {
        int i = t - E;
        int slot = atomicAdd(&cursor[i], 1);
        srcs[slot] = i;
    }
}

// ---------------- weight/input prep: fp32 -> bf16 TRANSPOSED ([N][K]) ----------------
#define WBIG (1152 * IND)
#define WC1 (768 * HCC)
#define WC2 (192 * HCC)
#define XB_N (NN * IND)
#define PREP_TOTAL (WBIG + WC1 + WC2 + XB_N + 1152 + 768 + 192)

__global__ void prep_kernel(const float* __restrict__ x, const float* __restrict__ inp_w,
    const float* __restrict__ l0wl, const float* __restrict__ l0wr,
    const float* __restrict__ l1wl, const float* __restrict__ l1wr,
    const float* __restrict__ l2wl, const float* __restrict__ l2wr,
    const float* __restrict__ resw,
    const float* __restrict__ inp_b,
    const float* __restrict__ l0bl, const float* __restrict__ l0br,
    const float* __restrict__ l1bl, const float* __restrict__ l1br,
    const float* __restrict__ l2bl, const float* __restrict__ l2br,
    ushort_t* wBig, ushort_t* wC1, ushort_t* wC2, ushort_t* xb,
    float* bBig, float* bC1, float* bC2)
{
    int i = blockIdx.x * blockDim.x + threadIdx.x;
    if (i >= PREP_TOTAL) return;
    if (i < WBIG) {
        int col = i >> 7, k = i & 127;
        float v;
        if (col < 384)      v = inp_w[k * 384 + col];
        else if (col < 768) v = l0wl[k * 384 + (col - 384)];
        else                v = l0wr[k * 384 + (col - 768)];
        wBig[i] = f2bf(v); return;
    }
    i -= WBIG;
    if (i < WC1) {
        int col = i / 384, k = i - col * 384;
        float v = col < 384 ? l1wl[k * 384 + col] : l1wr[k * 384 + (col - 384)];
        wC1[i] = f2bf(v); return;
    }
    i -= WC1;
    if (i < WC2) {
        int col = i / 384, k = i - col * 384;
        float v;
        if (col < 64)       v = resw[k * 64 + col];
        else if (col < 128) v = l2wl[k * 64 + (col - 64)];
        else                v = l2wr[k * 64 + (col - 128)];
        wC2[i] = f2bf(v); return;
    }
    i -= WC2;
    if (i < XB_N) { xb[i] = f2bf(x[i]); return; }
    i -= XB_N;
    if (i < 1152) {
        float v;
        if (i < 384)      v = inp_b[i];
        else if (i < 768) v = l0bl[i - 384];
        else              v = l0br[i - 768];
        bBig[i] = v; return;
    }
    i -= 1152;
    if (i < 768) { bC1[i] = i < 384 ? l1bl[i] : l1br[i - 384]; return; }
    i -= 768;
    if (i < 192) {
        float v;
        if (i < 64)       v = 0.0f;
        else if (i < 128) v = l2bl[i - 64];
        else              v = l2br[i - 128];
        bC2[i] = v; return;
    }
}

// ---------------- bf16 MFMA GEMM: A direct-to-register, B-only LDS, BK=64 ----------------
__global__ __launch_bounds__(256) void gemm_mfma(
    const ushort_t* __restrict__ A, const ushort_t* __restrict__ BT,
    const float* __restrict__ bias,
    float* __restrict__ Cf, ushort_t* __restrict__ Cb1, int ld1,
    ushort_t* __restrict__ Cb2, int ld2, int split,
    int M, int N, int K)
{
    __shared__ ushort_t Bs[2][2][128 * 32];   // [buf][k-half][row*32+k]
    int t = threadIdx.x;
    int w = t >> 6, L = t & 63;
    int m0 = blockIdx.x * 128, n0 = blockIdx.y * 128;
    int q = L >> 4, r16 = L & 15;

    f32x4 acc[2][8];
#pragma unroll
    for (int a = 0; a < 2; ++a)
#pragma unroll
        for (int b = 0; b < 8; ++b) acc[a][b] = (f32x4){0.f, 0.f, 0.f, 0.f};

    int lr = L >> 2;
    int lc = (L & 3) * 8;
    int rB0 = min(n0 + w * 32 + lr, N - 1);
    int rB1 = min(n0 + w * 32 + 16 + lr, N - 1);
    const ushort_t* gB0 = BT + (size_t)rB0 * K + lc;
    const ushort_t* gB1 = BT + (size_t)rB1 * K + lc;
    int oB0 = (w * 32) * 32;
    int oB1 = (w * 32 + 16) * 32;

    int rA0 = min(m0 + w * 32 + r16, M - 1);
    int rA1 = min(m0 + w * 32 + 16 + r16, M - 1);
    const ushort_t* pA0 = A + (size_t)rA0 * K + q * 8;
    const ushort_t* pA1 = A + (size_t)rA1 * K + q * 8;

    load_lds16(gB0, &Bs[0][0][oB0]);
    load_lds16(gB1, &Bs[0][0][oB1]);
    load_lds16(gB0 + 32, &Bs[0][1][oB0]);
    load_lds16(gB1 + 32, &Bs[0][1][oB1]);
    gB0 += 64; gB1 += 64;
    bf16x8 a0 = *(const bf16x8*)pA0;
    bf16x8 a2 = *(const bf16x8*)(pA0 + 32);
    bf16x8 a1 = *(const bf16x8*)pA1;
    bf16x8 a3 = *(const bf16x8*)(pA1 + 32);
    pA0 += 64; pA1 += 64;

    int buf = 0;
    for (int k0 = 0; k0 < K; k0 += 64) {
        __syncthreads();
        bool more = (k0 + 64 < K);
        if (more) {
            int nb = buf ^ 1;
            load_lds16(gB0, &Bs[nb][0][oB0]);
            load_lds16(gB1, &Bs[nb][0][oB1]);
            load_lds16(gB0 + 32, &Bs[nb][1][oB0]);
            load_lds16(gB1 + 32, &Bs[nb][1][oB1]);
            gB0 += 64; gB1 += 64;
        }
        bf16x8 na0, na1, na2, na3;
        if (more) {
            na0 = *(const bf16x8*)pA0;
            na2 = *(const bf16x8*)(pA0 + 32);
            na1 = *(const bf16x8*)pA1;
            na3 = *(const bf16x8*)(pA1 + 32);
            pA0 += 64; pA1 += 64;
        }
#pragma unroll
        for (int ct = 0; ct < 8; ++ct) {
            bf16x8 blo = *(const bf16x8*)&Bs[buf][0][(ct * 16 + r16) * 32 + q * 8];
            bf16x8 bhi = *(const bf16x8*)&Bs[buf][1][(ct * 16 + r16) * 32 + q * 8];
            acc[0][ct] = __builtin_amdgcn_mfma_f32_16x16x32_bf16(a0, blo, acc[0][ct], 0, 0, 0);
            acc[1][ct] = __builtin_amdgcn_mfma_f32_16x16x32_bf16(a1, blo, acc[1][ct], 0, 0, 0);
            acc[0][ct] = __builtin_amdgcn_mfma_f32_16x16x32_bf16(a2, bhi, acc[0][ct], 0, 0, 0);
            acc[1][ct] = __builtin_amdgcn_mfma_f32_16x16x32_bf16(a3, bhi, acc[1][ct], 0, 0, 0);
        }
        if (more) { a0 = na0; a1 = na1; a2 = na2; a3 = na3; }
        buf ^= 1;
    }
#pragma unroll
    for (int rt = 0; rt < 2; ++rt) {
#pragma unroll
        for (int ct = 0; ct < 8; ++ct) {
            int col = n0 + ct * 16 + r16;
            if (col < N) {
                float bv = bias ? bias[col] : 0.0f;
#pragma unroll
                for (int rr = 0; rr < 4; ++rr) {
                    int row = m0 + w * 32 + rt * 16 + q * 4 + rr;
                    if (row < M) {
                        float v = acc[rt][ct][rr] + bv;
                        if (col < split) {
                            if (Cf) Cf[(size_t)row * ld1 + col] = v;
                            else    Cb1[(size_t)row * ld1 + col] = f2bf(v);
                        } else {
                            Cb2[(size_t)row * ld2 + (col - split)] = f2bf(v);
                        }
                    }
                }
            }
        }
    }
}

// ---------------- GATv2 H=6: single-pass, exp2-folded softmax, DPP reduce, pipelined ----------------
// r13 structure (linear wid). att pre-scaled by log2(e): exp(e) == exp2(e_scaled).
__global__ __launch_bounds__(256) void gat6_kernel(
    const ushort_t* __restrict__ cat, const float* __restrict__ att,
    const float* __restrict__ bias, const ushort_t* __restrict__ resB,
    ushort_t* __restrict__ outB,
    const int* __restrict__ offsets, const int* __restrict__ srcs, int n)
{
    int wid = (blockIdx.x * blockDim.x + threadIdx.x) >> 6;
    if (wid >= n) return;
    int lane = threadIdx.x & 63;
    int h = lane >> 3, c8 = lane & 7;
    int off = h * 64 + c8 * 8;
    bool hv = h < HH;
    int i = wid;
    int beg = offsets[i], end = offsets[i + 1];

    f32x2 xr2[4], att2[4];
    {
        uint4 v = make_uint4(0u, 0u, 0u, 0u);
        if (hv) v = *(const uint4*)(cat + (size_t)i * 768 + 384 + off);
        bf8cvt2(v, xr2);
    }
#pragma unroll
    for (int j = 0; j < 4; ++j) {
        float a0 = hv ? att[off + 2 * j] * LOG2E : 0.0f;
        float a1 = hv ? att[off + 2 * j + 1] * LOG2E : 0.0f;
        att2[j] = (f32x2){a0, a1};
    }

    float s = 0.0f;
    f32x2 acc2[4];
#pragma unroll
    for (int j = 0; j < 4; ++j) acc2[j] = (f32x2){0.f, 0.f};

    const uint4 z = make_uint4(0u, 0u, 0u, 0u);
    int deg = end - beg;
    int npair = deg >> 1;
    bool odd = (deg & 1) != 0;

    uint4 cA = z, cB = z;
    int iA1 = 0, iB1 = 0;

    if (npair > 0) {
        int iA0 = srcs[beg], iB0 = srcs[beg + 1];
        if (npair > 1)      { iA1 = srcs[beg + 2]; iB1 = srcs[beg + 3]; }
        else if (odd)       { iA1 = srcs[beg + 2]; }
        if (hv) {
            cA = *(const uint4*)(cat + (size_t)iA0 * 768 + off);
            cB = *(const uint4*)(cat + (size_t)iB0 * 768 + off);
        }
    } else if (odd) {
        int i0 = srcs[beg];
        if (hv) cA = *(const uint4*)(cat + (size_t)i0 * 768 + off);
    }

    for (int g = 0; g < npair; ++g) {
        int base2 = beg + 2 * (g + 2);
        int niA = 0, niB = 0;
        if (g + 2 < npair)                { niA = srcs[base2]; niB = srcs[base2 + 1]; }
        else if (g + 2 == npair && odd)   { niA = srcs[base2]; }
        uint4 nA = z, nB = z;
        bool haveN = (g + 1 < npair);
        bool haveT = (g + 1 == npair) && odd;
        if (hv) {
            if (haveN) {
                nA = *(const uint4*)(cat + (size_t)iA1 * 768 + off);
                nB = *(const uint4*)(cat + (size_t)iB1 * 768 + off);
            } else if (haveT) {
                nA = *(const uint4*)(cat + (size_t)iA1 * 768 + off);
            }
        }
        f32x2 xlA[4], xlB[4];
        bf8cvt2(cA, xlA);
        bf8cvt2(cB, xlB);
        f32x2 pA2 = (f32x2){0.f, 0.f}, pB2 = (f32x2){0.f, 0.f};
#pragma unroll
        for (int j = 0; j < 4; ++j) {
            f32x2 ta = xlA[j] + xr2[j];
            ta = __builtin_elementwise_max(ta, ta * 0.2f);
            pA2 += ta * att2[j];
            f32x2 tb = xlB[j] + xr2[j];
            tb = __builtin_elementwise_max(tb, tb * 0.2f);
            pB2 += tb * att2[j];
        }
        float pA = pA2.x + pA2.y, pB = pB2.x + pB2.y;
        pA = dppadd<0xB1>(pA);
        pB = dppadd<0xB1>(pB);
        pA = dppadd<0x4E>(pA);
        pB = dppadd<0x4E>(pB);
        pA = dppadd<0x141>(pA);
        pB = dppadd<0x141>(pB);
        float wA = __builtin_amdgcn_exp2f(pA);
        float wB = __builtin_amdgcn_exp2f(pB);
        s += wA + wB;
        f32x2 wA2 = (f32x2){wA, wA}, wB2 = (f32x2){wB, wB};
#pragma unroll
        for (int j = 0; j < 4; ++j) {
            acc2[j] += wA2 * xlA[j];
            acc2[j] += wB2 * xlB[j];
        }
        cA = nA; cB = nB;
        iA1 = niA; iB1 = niB;
    }
    if (odd) {
        f32x2 xl[4];
        bf8cvt2(cA, xl);
        f32x2 pp2 = (f32x2){0.f, 0.f};
#pragma unroll
        for (int j = 0; j < 4; ++j) {
            f32x2 tv = xl[j] + xr2[j];
            tv = __builtin_elementwise_max(tv, tv * 0.2f);
            pp2 += tv * att2[j];
        }
        float pp = pp2.x + pp2.y;
        pp = dppadd<0xB1>(pp);
        pp = dppadd<0x4E>(pp);
        pp = dppadd<0x141>(pp);
        float wE = __builtin_amdgcn_exp2f(pp);
        s += wE;
        f32x2 w2 = (f32x2){wE, wE};
#pragma unroll
        for (int j = 0; j < 4; ++j) acc2[j] += w2 * xl[j];
    }

    if (hv) {
        float inv = 1.0f / (s + 1e-16f);
        size_t ob = (size_t)i * HCC + off;
        uint4 rv = *(const uint4*)(resB + ob);
        f32x2 rr[4];
        bf8cvt2(rv, rr);
        ushort_t u[8];
#pragma unroll
        for (int j = 0; j < 4; ++j) {
            float v0 = acc2[j].x * inv + bias[off + 2 * j];
            float v1 = acc2[j].y * inv + bias[off + 2 * j + 1];
            v0 = v0 > 0.0f ? v0 : expm1f(v0);
            v1 = v1 > 0.0f ? v1 : expm1f(v1);
            u[2 * j]     = f2bf(v0 + rr[j].x);
            u[2 * j + 1] = f2bf(v1 + rr[j].y);
        }
        *(uint4*)(outB + ob) = *(uint4*)u;
    }
}

// ---------------- GATv2 H=1: single-pass exp2-folded, DPP reduce, prefetched ----------------
__global__ __launch_bounds__(256) void gat1_kernel(
    const ushort_t* __restrict__ cat, const float* __restrict__ att,
    const float* __restrict__ bias, const float* __restrict__ res,
    float* __restrict__ out,
    const int* __restrict__ offsets, const int* __restrict__ srcs, int n)
{
    int wid = (blockIdx.x * blockDim.x + threadIdx.x) >> 6;
    if (wid >= n) return;
    int lane = threadIdx.x & 63;
    int e8 = lane >> 3, c8 = lane & 7;
    int i = wid;
    int beg = offsets[i], end = offsets[i + 1];

    f32x2 xr2[4], att2[4];
    {
        uint4 v = *(const uint4*)(cat + (size_t)i * 128 + 64 + c8 * 8);
        bf8cvt2(v, xr2);
    }
#pragma unroll
    for (int j = 0; j < 4; ++j)
        att2[j] = (f32x2){att[c8 * 8 + 2 * j] * LOG2E, att[c8 * 8 + 2 * j + 1] * LOG2E};

    float s = 0.0f;
    f32x2 acc2[4];
#pragma unroll
    for (int j = 0; j < 4; ++j) acc2[j] = (f32x2){0.f, 0.f};

    const uint4 z = make_uint4(0u, 0u, 0u, 0u);
    int p = beg + e8;
    bool val = p < end;
    int sj = val ? srcs[p] : i;
    uint4 v = *(const uint4*)(cat + (size_t)sj * 128 + c8 * 8);

    for (int p0 = beg; p0 < end; p0 += 8) {
        uint4 nv = z;
        bool nval = false;
        if (p0 + 8 < end) {
            int np = p0 + 8 + e8;
            nval = np < end;
            int nsj = nval ? srcs[np] : i;
            nv = *(const uint4*)(cat + (size_t)nsj * 128 + c8 * 8);
        }
        f32x2 xl[4];
        bf8cvt2(v, xl);
        f32x2 pp2 = (f32x2){0.f, 0.f};
#pragma unroll
        for (int j = 0; j < 4; ++j) {
            f32x2 tv = xl[j] + xr2[j];
            tv = __builtin_elementwise_max(tv, tv * 0.2f);
            pp2 += tv * att2[j];
        }
        float partial = pp2.x + pp2.y;
        partial = dppadd<0xB1>(partial);
        partial = dppadd<0x4E>(partial);
        partial = dppadd<0x141>(partial);
        float wE = val ? __builtin_amdgcn_exp2f(partial) : 0.0f;
        s += wE;
        f32x2 w2 = (f32x2){wE, wE};
#pragma unroll
        for (int j = 0; j < 4; ++j) acc2[j] += w2 * xl[j];
        v = nv;
        val = nval;
    }

    s = dppadd<0x140>(s);
    s += __shfl_xor(s, 16, 64);
    s += __shfl_xor(s, 32, 64);
#pragma unroll
    for (int j = 0; j < 4; ++j) {
        acc2[j].x += __shfl_xor(acc2[j].x, 8, 64);
        acc2[j].y += __shfl_xor(acc2[j].y, 8, 64);
        acc2[j].x += __shfl_xor(acc2[j].x, 16, 64);
        acc2[j].y += __shfl_xor(acc2[j].y, 16, 64);
        acc2[j].x += __shfl_xor(acc2[j].x, 32, 64);
        acc2[j].y += __shfl_xor(acc2[j].y, 32, 64);
    }
    if (e8 == 0) {
        float inv = 1.0f / (s + 1e-16f);
        size_t ob = (size_t)i * CC + c8 * 8;
        float4 r0 = *(const float4*)(res + ob);
        float4 r1 = *(const float4*)(res + ob + 4);
        float rr[8] = {r0.x, r0.y, r0.z, r0.w, r1.x, r1.y, r1.z, r1.w};
        float av[8] = {acc2[0].x, acc2[0].y, acc2[1].x, acc2[1].y,
                       acc2[2].x, acc2[2].y, acc2[3].x, acc2[3].y};
#pragma unroll
        for (int j = 0; j < 8; ++j) {
            float v2 = av[j] * inv + bias[c8 * 8 + j];
            v2 = v2 > 0.0f ? v2 : expm1f(v2);
            av[j] = v2 + rr[j];
        }
        *(float4*)(out + ob) = make_float4(av[0], av[1], av[2], av[3]);
        *(float4*)(out + ob + 4) = make_float4(av[4], av[5], av[6], av[7]);
    }
}

// ---------------- pooling (batch is sorted) ----------------
__global__ void pool_kernel(const float* __restrict__ h, const int* __restrict__ batch,
                            float* __restrict__ pooled, int n) {
    const int CHUNK = 128;
    int start = blockIdx.x * CHUNK;
    int lane = threadIdx.x;  // 64
    if (start >= n) return;
    int end = start + CHUNK;
    if (end > n) end = n;
    float acc = 0.0f;
    int cur = batch[start];
    for (int i = start; i < end; ++i) {
        int g = batch[i];
        if (g != cur) {
            atomicAdd(&pooled[cur * 64 + lane], acc);
            acc = 0.0f;
            cur = g;
        }
        acc += h[(size_t)i * 64 + lane];
    }
    atomicAdd(&pooled[cur * 64 + lane], acc);
}

// ---------------- dense head ----------------
__global__ void head_kernel(const float* __restrict__ pooled,
                            const float* __restrict__ d1w, const float* __restrict__ d1b,
                            const float* __restrict__ bng, const float* __restrict__ bnb,
                            const float* __restrict__ bnm, const float* __restrict__ bnv,
                            const float* __restrict__ d2w, const float* __restrict__ d2b,
                            float* __restrict__ zout) {
    __shared__ float z1[64 * 64];
    int t = threadIdx.x;  // 256
    for (int idx = t; idx < 64 * 64; idx += 256) {
        int r = idx >> 6, c = idx & 63;
        float acc = d1b[c];
        for (int k = 0; k < 64; ++k) acc += pooled[r * 64 + k] * d1w[k * 64 + c];
        acc = (acc - bnm[c]) / sqrtf(bnv[c] + 1e-5f) * bng[c] + bnb[c];
        z1[idx] = acc > 0.0f ? acc : 0.0f;
    }
    __syncthreads();
    for (int idx = t; idx < 64 * NCC; idx += 256) {
        int r = idx >> 4, c = idx & 15;
        float acc = d2b[c];
        for (int k = 0; k < 64; ++k) acc += z1[r * 64 + k] * d2w[k * NCC + c];
        zout[idx] = acc;
    }
}

// ---------------- launcher ----------------

extern "C" void kernel_launch(void* const* d_in, const int* in_sizes, int n_in,
                              void* d_out, int out_size, void* d_ws, size_t ws_size,
                              hipStream_t stream) {
    const int N = NN, E = EE, C = CC, HC = HCC, NG = NGG;
    const int EN = E + N;

    const float* x     = (const float*)d_in[0];
    const int*   ei    = (const int*)d_in[1];
    const int*   batch = (const int*)d_in[2];
    const float* inp_w = (const float*)d_in[3];
    const float* inp_b = (const float*)d_in[4];
    const float* l0_wl = (const float*)d_in[5];
    const float* l0_bl = (const float*)d_in[6];
    const float* l0_wr = (const float*)d_in[7];
    const float* l0_br = (const float*)d_in[8];
    const float* l0_att = (const float*)d_in[9];
    const float* l0_bias = (const float*)d_in[10];
    const float* l1_wl = (const float*)d_in[11];
    const float* l1_bl = (const float*)d_in[12];
    const float* l1_wr = (const float*)d_in[13];
    const float* l1_br = (const float*)d_in[14];
    const float* l1_att = (const float*)d_in[15];
    const float* l1_bias = (const float*)d_in[16];
    const float* l2_wl = (const float*)d_in[17];
    const float* l2_bl = (const float*)d_in[18];
    const float* l2_wr = (const float*)d_in[19];
    const float* l2_br = (const float*)d_in[20];
    const float* l2_att = (const float*)d_in[21];
    const float* l2_bias = (const float*)d_in[22];
    const float* res_w = (const float*)d_in[23];
    const float* d1_w = (const float*)d_in[24];
    const float* d1_b = (const float*)d_in[25];
    const float* bn_g = (const float*)d_in[26];
    const float* bn_b = (const float*)d_in[27];
    const float* bn_m = (const float*)d_in[28];
    const float* bn_v = (const float*)d_in[29];
    const float* d2_w = (const float*)d_in[30];
    const float* d2_b = (const float*)d_in[31];

    float* out = (float*)d_out;

    char* ws = (char*)d_ws;
    size_t off = 0;
    auto alloc = [&](size_t bytes) -> void* {
        void* p = ws + off;
        off += (bytes + 255) & ~(size_t)255;
        return p;
    };
    ushort_t* bufH_b  = (ushort_t*)alloc((size_t)N * HC * 2);
    ushort_t* cat01_b = (ushort_t*)alloc((size_t)N * 768 * 2 + 2048);
    ushort_t* xres_b  = (ushort_t*)alloc((size_t)N * HC * 2);
    ushort_t* cat2_b  = (ushort_t*)alloc((size_t)N * 128 * 2);
    float*    bufRes  = (float*)alloc((size_t)N * C * 4);
    ushort_t* xb      = (ushort_t*)alloc((size_t)N * IND * 2);
    ushort_t* wBig    = (ushort_t*)alloc((size_t)WBIG * 2);
    ushort_t* wC1     = (ushort_t*)alloc((size_t)WC1 * 2);
    ushort_t* wC2     = (ushort_t*)alloc((size_t)WC2 * 2);
    float*    bBig    = (float*)alloc((size_t)1152 * 4);
    float*    bC1     = (float*)alloc((size_t)768 * 4);
    float*    bC2     = (float*)alloc((size_t)192 * 4);
    int*      counts  = (int*)alloc((size_t)N * 4);
    int*      cursor  = (int*)alloc((size_t)N * 4);
    int*      offsets = (int*)alloc((size_t)(N + 1) * 4);
    int*      srcs    = (int*)alloc((size_t)EN * 4);
    float*    pooled  = (float*)alloc((size_t)NG * C * 4);

    int zi_n = N > NG * C ? N : NG * C;
    zero_init_kernel<<<(zi_n + 255) / 256, 256, 0, stream>>>(counts, pooled, N, NG * C);
    count_kernel<<<(E + 255) / 256, 256, 0, stream>>>(ei, counts, E);
    scan_kernel<<<1, 1024, 0, stream>>>(counts, offsets, cursor, N);
    fill_kernel<<<(EN + 255) / 256, 256, 0, stream>>>(ei, cursor, srcs, E, N);
    prep_kernel<<<(PREP_TOTAL + 255) / 256, 256, 0, stream>>>(
        x, inp_w, l0_wl, l0_wr, l1_wl, l1_wr, l2_wl, l2_wr, res_w,
        inp_b, l0_bl, l0_br, l1_bl, l1_br, l2_bl, l2_br,
        wBig, wC1, wC2, xb, bBig, bC1, bC2);

    dim3 blk(256);
    int mtiles = (N + 127) / 128;
    int gatBlocks = (N * 64 + 255) / 256;

    // fused: [x_res | l0_xl | l0_xr] = xb @ wBig (all bf16 out; split at 384)
    gemm_mfma<<<dim3(mtiles, 9), blk, 0, stream>>>(xb, wBig, bBig,
        nullptr, xres_b, HC, cat01_b, 768, 384, N, 1152, IND);
    gat6_kernel<<<gatBlocks, blk, 0, stream>>>(cat01_b, l0_att, l0_bias,
                                               xres_b, bufH_b, offsets, srcs, N);
    // layer 1: [l1_xl | l1_xr] = h0 @ wC1
    gemm_mfma<<<dim3(mtiles, 6), blk, 0, stream>>>(bufH_b, wC1, bC1,
        nullptr, nullptr, 0, cat01_b, 768, 0, N, 768, HC);
    gat6_kernel<<<gatBlocks, blk, 0, stream>>>(cat01_b, l1_att, l1_bias,
                                               bufH_b, bufH_b, offsets, srcs, N);
    // fused: [res | l2_xl | l2_xr] = h1 @ wC2 (res fp32, rest bf16)
    gemm_mfma<<<dim3(mtiles, 2), blk, 0, stream>>>(bufH_b, wC2, bC2,
        bufRes, nullptr, C, cat2_b, 128, 64, N, 192, HC);
    gat1_kernel<<<gatBlocks, blk, 0, stream>>>(cat2_b, l2_att, l2_bias,
                                               bufRes, out, offsets, srcs, N);
    // pooling + head
    pool_kernel<<<(N + 127) / 128, 64, 0, stream>>>(out, batch, pooled, N);
    head_kernel<<<1, 256, 0, stream>>>(pooled, d1_w, d1_b, bn_g, bn_b, bn_m, bn_v,
                                       d2_w, d2_b, out + (size_t)N * C);
}